// Round 1
// baseline (191.000 us; speedup 1.0000x reference)
//
#include <hip/hip_runtime.h>
#include <math.h>

#define NN 1024
#define CC 256
#define TT 64

// ---------------- block reduction helpers ----------------

__device__ __forceinline__ float blockReduceSum(float v) {
    __shared__ float tmp[4];
    #pragma unroll
    for (int o = 32; o > 0; o >>= 1) v += __shfl_down(v, o, 64);
    int lane = threadIdx.x & 63;
    int w = threadIdx.x >> 6;
    __syncthreads();               // safe reuse across successive calls
    if (lane == 0) tmp[w] = v;
    __syncthreads();
    return tmp[0] + tmp[1] + tmp[2] + tmp[3];
}

// ---------------- kernel 1: time-mean ----------------
// 2 tensors x (N*T*C) -> x,y (N*C). One thread per (tensor, n, c4[float4]).
// threads = 2 * 1024 * 64 = 131072 -> 512 blocks of 256.
__global__ __launch_bounds__(256) void mean_kernel(
    const float* __restrict__ in0, const float* __restrict__ in1,
    float* __restrict__ x, float* __restrict__ y) {
    int idx = blockIdx.x * 256 + threadIdx.x;
    int m = idx >> 16;            // 0: output_1 -> x, 1: feature -> y
    int rem = idx & 65535;
    int n = rem >> 6;             // row
    int c4 = rem & 63;            // float4 channel index
    const float4* src = (const float4*)((m ? in1 : in0) + (size_t)n * (TT * CC)) + c4;
    float4 s = make_float4(0.f, 0.f, 0.f, 0.f);
    #pragma unroll 16
    for (int t = 0; t < TT; ++t) {
        float4 v = src[t * (CC / 4)];
        s.x += v.x; s.y += v.y; s.z += v.z; s.w += v.w;
    }
    const float inv = 1.0f / TT;
    s.x *= inv; s.y *= inv; s.z *= inv; s.w *= inv;
    ((float4*)(m ? y : x))[n * (CC / 4) + c4] = s;
}

// ---------------- kernel 2: squared row norms ----------------
// 2048 blocks; block b: row b of x (b<1024) or y. 256 threads = C channels.
__global__ __launch_bounds__(256) void norm_kernel(
    const float* __restrict__ x, const float* __restrict__ y,
    float* __restrict__ nx, float* __restrict__ ny) {
    int row = blockIdx.x;
    const float* z = (row < NN) ? x : y;
    float* out = (row < NN) ? nx : ny;
    int r = row & (NN - 1);
    float v = z[r * CC + threadIdx.x];
    float s = blockReduceSum(v * v);
    if (threadIdx.x == 0) out[r] = s;
}

// ---------------- kernel 3: pairwise distances ----------------
// 64x64 tile per block, 16x16 threads, 4x4 microtile.
// d[i][j] = sqrt(max(|xi|^2+|xj|^2-2*xi.xj, 0) + 1e-12)
__global__ __launch_bounds__(256) void dist_kernel(
    const float* __restrict__ x, const float* __restrict__ y,
    const float* __restrict__ nx, const float* __restrict__ ny,
    float* __restrict__ dx, float* __restrict__ dy) {
    const float* z; const float* nrm; float* d;
    if (blockIdx.z == 0) { z = x; nrm = nx; d = dx; }
    else                 { z = y; nrm = ny; d = dy; }

    __shared__ float sa[64][65];
    __shared__ float sb[64][65];

    int tid = threadIdx.x;
    int tx = tid & 15, ty = tid >> 4;
    int ti = blockIdx.y * 64, tj = blockIdx.x * 64;

    float acc[4][4] = {};

    for (int cc = 0; cc < CC; cc += 64) {
        __syncthreads();
        #pragma unroll
        for (int s = 0; s < 4; ++s) {
            int f4 = tid + s * 256;           // 0..1023
            int r = f4 >> 4;                  // 0..63
            int c4 = f4 & 15;                 // 0..15
            float4 va = *(const float4*)(z + (ti + r) * CC + cc + c4 * 4);
            sa[r][c4 * 4 + 0] = va.x; sa[r][c4 * 4 + 1] = va.y;
            sa[r][c4 * 4 + 2] = va.z; sa[r][c4 * 4 + 3] = va.w;
            float4 vb = *(const float4*)(z + (tj + r) * CC + cc + c4 * 4);
            sb[r][c4 * 4 + 0] = vb.x; sb[r][c4 * 4 + 1] = vb.y;
            sb[r][c4 * 4 + 2] = vb.z; sb[r][c4 * 4 + 3] = vb.w;
        }
        __syncthreads();
        #pragma unroll 8
        for (int ch = 0; ch < 64; ++ch) {
            float a0 = sa[4 * ty + 0][ch];
            float a1 = sa[4 * ty + 1][ch];
            float a2 = sa[4 * ty + 2][ch];
            float a3 = sa[4 * ty + 3][ch];
            float b0 = sb[4 * tx + 0][ch];
            float b1 = sb[4 * tx + 1][ch];
            float b2 = sb[4 * tx + 2][ch];
            float b3 = sb[4 * tx + 3][ch];
            acc[0][0] += a0 * b0; acc[0][1] += a0 * b1; acc[0][2] += a0 * b2; acc[0][3] += a0 * b3;
            acc[1][0] += a1 * b0; acc[1][1] += a1 * b1; acc[1][2] += a1 * b2; acc[1][3] += a1 * b3;
            acc[2][0] += a2 * b0; acc[2][1] += a2 * b1; acc[2][2] += a2 * b2; acc[2][3] += a2 * b3;
            acc[3][0] += a3 * b0; acc[3][1] += a3 * b1; acc[3][2] += a3 * b2; acc[3][3] += a3 * b3;
        }
    }

    float ni[4], nj[4];
    #pragma unroll
    for (int p = 0; p < 4; ++p) ni[p] = nrm[ti + 4 * ty + p];
    #pragma unroll
    for (int q = 0; q < 4; ++q) nj[q] = nrm[tj + 4 * tx + q];

    #pragma unroll
    for (int p = 0; p < 4; ++p) {
        float4 o;
        o.x = sqrtf(fmaxf(ni[p] + nj[0] - 2.f * acc[p][0], 0.f) + 1e-12f);
        o.y = sqrtf(fmaxf(ni[p] + nj[1] - 2.f * acc[p][1], 0.f) + 1e-12f);
        o.z = sqrtf(fmaxf(ni[p] + nj[2] - 2.f * acc[p][2], 0.f) + 1e-12f);
        o.w = sqrtf(fmaxf(ni[p] + nj[3] - 2.f * acc[p][3], 0.f) + 1e-12f);
        ((float4*)(d + (size_t)(ti + 4 * ty + p) * NN + tj))[tx] = o;
    }
}

// ---------------- kernel 4: row sums of d ----------------
__global__ __launch_bounds__(256) void rowsum_kernel(
    const float* __restrict__ dx, const float* __restrict__ dy,
    float* __restrict__ rx, float* __restrict__ ry) {
    int row = blockIdx.x;
    const float* d = (row < NN) ? dx : dy;
    float* out = (row < NN) ? rx : ry;
    int r = row & (NN - 1);
    float s = 0.f;
    #pragma unroll
    for (int jj = 0; jj < NN; jj += 256) s += d[(size_t)r * NN + jj + threadIdx.x];
    s = blockReduceSum(s);
    if (threadIdx.x == 0) out[r] = s;
}

// ---------------- kernel 5: total means ----------------
__global__ __launch_bounds__(256) void totals_kernel(
    const float* __restrict__ rx, const float* __restrict__ ry,
    float* __restrict__ tm) {
    float sx = 0.f, sy = 0.f;
    for (int i = threadIdx.x; i < NN; i += 256) { sx += rx[i]; sy += ry[i]; }
    sx = blockReduceSum(sx);
    sy = blockReduceSum(sy);
    if (threadIdx.x == 0) {
        const double inv = 1.0 / ((double)NN * (double)NN);
        tm[0] = (float)(sx * inv);
        tm[1] = (float)(sy * inv);
    }
}

// ---------------- kernel 6: centered products, per-row partials ----------------
__global__ __launch_bounds__(256) void final_kernel(
    const float* __restrict__ dx, const float* __restrict__ dy,
    const float* __restrict__ rx, const float* __restrict__ ry,
    const float* __restrict__ tm,
    float* __restrict__ pab, float* __restrict__ paa, float* __restrict__ pbb) {
    int i = blockIdx.x;
    const float invN = 1.0f / NN;
    float cx = tm[0] - rx[i] * invN;
    float cy = tm[1] - ry[i] * invN;
    float ab = 0.f, aa = 0.f, bb = 0.f;
    #pragma unroll
    for (int jj = 0; jj < NN; jj += 256) {
        int j = jj + threadIdx.x;
        float a = dx[(size_t)i * NN + j] - rx[j] * invN + cx;
        float b = dy[(size_t)i * NN + j] - ry[j] * invN + cy;
        ab += a * b; aa += a * a; bb += b * b;
    }
    ab = blockReduceSum(ab);
    aa = blockReduceSum(aa);
    bb = blockReduceSum(bb);
    if (threadIdx.x == 0) { pab[i] = ab; paa[i] = aa; pbb[i] = bb; }
}

// ---------------- kernel 7: final scalar ----------------
__global__ __launch_bounds__(256) void scalar_kernel(
    const float* __restrict__ pab, const float* __restrict__ paa,
    const float* __restrict__ pbb, float* __restrict__ out) {
    double ab = 0.0, aa = 0.0, bb = 0.0;
    for (int i = threadIdx.x; i < NN; i += 256) {
        ab += (double)pab[i]; aa += (double)paa[i]; bb += (double)pbb[i];
    }
    #pragma unroll
    for (int o = 32; o > 0; o >>= 1) {
        ab += __shfl_down(ab, o, 64);
        aa += __shfl_down(aa, o, 64);
        bb += __shfl_down(bb, o, 64);
    }
    __shared__ double t[12];
    int lane = threadIdx.x & 63, w = threadIdx.x >> 6;
    if (lane == 0) { t[w] = ab; t[4 + w] = aa; t[8 + w] = bb; }
    __syncthreads();
    if (threadIdx.x == 0) {
        ab = t[0] + t[1] + t[2] + t[3];
        aa = t[4] + t[5] + t[6] + t[7];
        bb = t[8] + t[9] + t[10] + t[11];
        const double inv = 1.0 / ((double)NN * (double)NN);
        double mab = ab * inv, maa = aa * inv, mbb = bb * inv;
        double r = mab / sqrt(maa * mbb + 1e-9);
        out[0] = (float)(1.0 - r);
    }
}

extern "C" void kernel_launch(void* const* d_in, const int* in_sizes, int n_in,
                              void* d_out, int out_size, void* d_ws, size_t ws_size,
                              hipStream_t stream) {
    const float* in0 = (const float*)d_in[0];   // output_1 (N,T,C) fp32
    const float* in1 = (const float*)d_in[1];   // feature  (N,T,C) fp32
    // d_in[2] (mask) is unused by the reference.

    char* ws = (char*)d_ws;
    float* x   = (float*)(ws);                      // 1 MB
    float* y   = (float*)(ws + (1u << 20));         // 1 MB
    float* nx  = (float*)(ws + (2u << 20));         // 4 KB
    float* ny  = nx + NN;
    float* rx  = ny + NN;
    float* ry  = rx + NN;
    float* tm  = ry + NN;                            // 2 floats (+pad)
    float* pab = tm + 16;
    float* paa = pab + NN;
    float* pbb = paa + NN;
    float* dx  = (float*)(ws + (4u << 20));         // 4 MB
    float* dy  = (float*)(ws + (8u << 20));         // 4 MB

    mean_kernel<<<512, 256, 0, stream>>>(in0, in1, x, y);
    norm_kernel<<<2 * NN, 256, 0, stream>>>(x, y, nx, ny);
    dist_kernel<<<dim3(16, 16, 2), 256, 0, stream>>>(x, y, nx, ny, dx, dy);
    rowsum_kernel<<<2 * NN, 256, 0, stream>>>(dx, dy, rx, ry);
    totals_kernel<<<1, 256, 0, stream>>>(rx, ry, tm);
    final_kernel<<<NN, 256, 0, stream>>>(dx, dy, rx, ry, tm, pab, paa, pbb);
    scalar_kernel<<<1, 256, 0, stream>>>(pab, paa, pbb, (float*)d_out);
}